// Round 1
// baseline (160.268 us; speedup 1.0000x reference)
//
#include <hip/hip_runtime.h>

#define BATCH 8
#define CIN 128
#define OCH 128
#define T_LEN 16384
#define NS 256
#define CHUNK 64
#define NCHUNK (T_LEN / CHUNK)   // 256
#define THALF (T_LEN / 2)        // 8192

typedef __attribute__((ext_vector_type(8))) short bf16x8;
typedef __attribute__((ext_vector_type(4))) float f32x4;
typedef __attribute__((ext_vector_type(4))) unsigned int u32x4;

__device__ __forceinline__ unsigned short f2bf(float f) {
  unsigned int u = __float_as_uint(f);
  u += 0x7fffu + ((u >> 16) & 1u);           // RNE
  return (unsigned short)(u >> 16);
}
__device__ __forceinline__ float bf2f(unsigned int h) {
  return __uint_as_float(h << 16);
}
__device__ __forceinline__ float softplusf_(float v) {
  return (v > 20.0f) ? v : log1pf(expf(v));
}
// XOR swizzles (16B-chunk granularity), bijective per row
__device__ __forceinline__ int xt_idx(int t, int c)  { return t * 128 + (c ^ ((t  & 7) << 3)); } // bf16 elems
__device__ __forceinline__ int v2_idx(int tp, int n) { return tp * 256 + (n ^ ((tp & 7) << 2)); } // u32 elems
__device__ __forceinline__ int hr_idx(int t2, int o) { return t2 * 128 + (o ^ ((t2 & 7) << 2)); } // u32 elems

// ---------------- prep: weights -> bf16, A_d, A_d^L ----------------
__global__ __launch_bounds__(256) void k_prep(
    const float* __restrict__ rl, const float* __restrict__ Bc,
    const float* __restrict__ Cm, const float* __restrict__ W,
    unsigned short* __restrict__ BdT, unsigned short* __restrict__ CT,
    unsigned short* __restrict__ Wb, float* __restrict__ Ad, float* __restrict__ rL)
{
  const int tid = blockIdx.x * 256 + threadIdx.x;
  if (tid < NS * CIN) {                       // BdT[n][c] = B_c[c][n] * (A_d-1)/lam
    const int n = tid >> 7, c = tid & 127;
    float lam = -softplusf_(rl[n]);
    float ad = expf(lam);
    float sc = (ad - 1.0f) / lam;
    BdT[tid] = f2bf(Bc[c * NS + n] * sc);
  } else if (tid < 2 * NS * CIN) {            // CT[o][n] = C[n][o]
    const int i = tid - NS * CIN;
    const int o = i >> 8, n = i & 255;
    CT[i] = f2bf(Cm[n * OCH + o]);
  } else if (tid < 3 * NS * CIN) {            // Wb[o][c2] = W[o][c2]
    const int i = tid - 2 * NS * CIN;
    Wb[i] = f2bf(W[i]);
  } else if (tid < 3 * NS * CIN + NS) {
    const int n = tid - 3 * NS * CIN;
    float lam = -softplusf_(rl[n]);
    Ad[n] = expf(lam);
    rL[n] = expf(lam * (float)CHUNK);
  }
}

// ---------------- chunk-carry combine: Hillis-Steele with multiplier A^L ----------------
__global__ __launch_bounds__(256) void k_combine(float* __restrict__ carry,
                                                 const float* __restrict__ rL)
{
  const int b = blockIdx.x >> 3;
  const int ng = blockIdx.x & 7;      // n-group of 32
  const int t = threadIdx.x;          // chunk index
  __shared__ float Y[32][NCHUNK];
  float* base = carry + ((size_t)b * NCHUNK + t) * NS + ng * 32;
  #pragma unroll
  for (int i4 = 0; i4 < 8; ++i4) {
    float4 q = *(const float4*)(base + i4 * 4);
    Y[i4 * 4 + 0][t] = q.x; Y[i4 * 4 + 1][t] = q.y;
    Y[i4 * 4 + 2][t] = q.z; Y[i4 * 4 + 3][t] = q.w;
  }
  float rp[32];
  #pragma unroll
  for (int i = 0; i < 32; ++i) rp[i] = rL[ng * 32 + i];
  __syncthreads();
  for (int d = 1; d < NCHUNK; d <<= 1) {
    float tmp[32];
    #pragma unroll
    for (int i = 0; i < 32; ++i) tmp[i] = (t >= d) ? Y[i][t - d] : 0.0f;
    __syncthreads();
    #pragma unroll
    for (int i = 0; i < 32; ++i) { Y[i][t] += rp[i] * tmp[i]; rp[i] *= rp[i]; }
    __syncthreads();
  }
  const int tm = (t == 0) ? 0 : (t - 1);
  #pragma unroll
  for (int i4 = 0; i4 < 8; ++i4) {
    float4 q;
    float a = Y[i4 * 4 + 0][tm], bb = Y[i4 * 4 + 1][tm];
    float c = Y[i4 * 4 + 2][tm], dd = Y[i4 * 4 + 3][tm];
    q.x = (t == 0) ? 0.0f : a;  q.y = (t == 0) ? 0.0f : bb;
    q.z = (t == 0) ? 0.0f : c;  q.w = (t == 0) ? 0.0f : dd;
    *(float4*)(base + i4 * 4) = q;
  }
}

// ---------------- main pass: FULL=0 -> chunk finals only; FULL=1 -> fused everything ----------------
template <int FULL>
__global__ __launch_bounds__(256, 2) void k_pass(
    const float* __restrict__ x,
    const unsigned short* __restrict__ BdT,
    const unsigned short* __restrict__ CT,
    const unsigned short* __restrict__ Wb,
    const float* __restrict__ Ad,
    float* __restrict__ carry,
    const float* __restrict__ lng, const float* __restrict__ lnb,
    const float* __restrict__ bias,
    float* __restrict__ out)
{
  const int bid = blockIdx.x;
  const int b = bid >> 8;               // batch
  const int kc = bid & (NCHUNK - 1);    // chunk
  const int t0 = kc * CHUNK;
  const int tid = threadIdx.x;
  const int w = tid >> 6;               // wave 0..3
  const int l = tid & 63;
  const int l15 = l & 15;
  const int g = l >> 4;

  extern __shared__ char smem[];
  unsigned short* Xt = (unsigned short*)smem;          // [64][128] bf16 swizzled
  unsigned int* V2 = (unsigned int*)(smem + 16384);    // [32][256] u32 (t-pair packed)

  // ---- stage x chunk transposed: Xt[t][c] = bf16(x[b][c][t0+t]) ----
  for (int i = tid; i < CHUNK * CIN; i += 256) {
    const int t = i & (CHUNK - 1);
    const int c = i >> 6;
    float v = x[((size_t)(b * CIN + c)) * T_LEN + (t0 + t)];
    Xt[xt_idx(t, c)] = f2bf(v);
  }
  __syncthreads();

  // ---- v GEMM: V[t][n] = Xt(64x128) . BdT^T ; wave w owns n in [64w, 64w+64) ----
  f32x4 acc[4][4] = {};
  #pragma unroll
  for (int kt = 0; kt < 4; ++kt) {
    const int kk = kt * 32 + g * 8;
    bf16x8 afr[4];
    #pragma unroll
    for (int mt = 0; mt < 4; ++mt)
      afr[mt] = *(const bf16x8*)&Xt[xt_idx(mt * 16 + l15, kk)];
    #pragma unroll
    for (int nt = 0; nt < 4; ++nt) {
      const int n = w * 64 + nt * 16 + l15;
      bf16x8 bfr = *(const bf16x8*)&BdT[n * CIN + kk];
      #pragma unroll
      for (int mt = 0; mt < 4; ++mt)
        acc[mt][nt] = __builtin_amdgcn_mfma_f32_16x16x32_bf16(afr[mt], bfr, acc[mt][nt], 0, 0, 0);
    }
  }
  // write packed t-pairs: V2[tp][n] = (v[2tp+1] , v[2tp])
  #pragma unroll
  for (int mt = 0; mt < 4; ++mt) {
    #pragma unroll
    for (int nt = 0; nt < 4; ++nt) {
      const int n = w * 64 + nt * 16 + l15;
      #pragma unroll
      for (int rp = 0; rp < 2; ++rp) {
        const int tp = mt * 8 + g * 2 + rp;
        unsigned int pk = ((unsigned int)f2bf(acc[mt][nt][rp * 2 + 1]) << 16)
                        |  (unsigned int)f2bf(acc[mt][nt][rp * 2]);
        V2[v2_idx(tp, n)] = pk;
      }
    }
  }
  __syncthreads();

  // ---- diagonal scan, thread owns state n = tid; overwrite v with s in place ----
  {
    const int n = tid;
    const float A = Ad[n];
    float s = 0.0f;
    if (FULL) s = carry[((size_t)b * NCHUNK + kc) * NS + n];
    #pragma unroll 8
    for (int tp = 0; tp < 32; ++tp) {
      const int idx = v2_idx(tp, n);
      unsigned int pk = V2[idx];
      float v0 = bf2f(pk & 0xffffu);
      float v1 = bf2f(pk >> 16);
      s = fmaf(s, A, v0);
      float s0 = s;
      s = fmaf(s, A, v1);
      if (FULL) V2[idx] = ((unsigned int)f2bf(s) << 16) | (unsigned int)f2bf(s0);
    }
    if (!FULL) carry[((size_t)b * NCHUNK + kc) * NS + n] = s;
  }
  if (!FULL) return;
  __syncthreads();

  // ---- y GEMM: wave w owns rows t in [16w, 16w+16), all 128 o ----
  f32x4 yac[8] = {};
  {
    const int trow = w * 16 + l15;
    const int tp = trow >> 1;
    const unsigned int sel = (trow & 1) ? 0x07060302u : 0x05040100u;
    #pragma unroll
    for (int kt = 0; kt < 8; ++kt) {
      const int n0 = kt * 32 + g * 8;
      u32x4 q0 = *(const u32x4*)&V2[v2_idx(tp, n0)];
      u32x4 q1 = *(const u32x4*)&V2[v2_idx(tp, n0 + 4)];
      union { bf16x8 v; unsigned int u[4]; } Af;
      Af.u[0] = __builtin_amdgcn_perm(q0[1], q0[0], sel);
      Af.u[1] = __builtin_amdgcn_perm(q0[3], q0[2], sel);
      Af.u[2] = __builtin_amdgcn_perm(q1[1], q1[0], sel);
      Af.u[3] = __builtin_amdgcn_perm(q1[3], q1[2], sel);
      #pragma unroll
      for (int ot = 0; ot < 8; ++ot) {
        const int o = ot * 16 + l15;
        bf16x8 bfr = *(const bf16x8*)&CT[o * NS + n0];
        yac[ot] = __builtin_amdgcn_mfma_f32_16x16x32_bf16(Af.v, bfr, yac[ot], 0, 0, 0);
      }
    }
  }

  // ---- LayerNorm (in-register 16-lane reduce) + SiLU + interleave into Hr2 ----
  {
    float mu[4], rs[4];
    #pragma unroll
    for (int r = 0; r < 4; ++r) {
      float s1 = 0.0f, s2 = 0.0f;
      #pragma unroll
      for (int ot = 0; ot < 8; ++ot) { float v = yac[ot][r]; s1 += v; s2 += v * v; }
      #pragma unroll
      for (int d = 1; d < 16; d <<= 1) {
        s1 += __shfl_xor(s1, d);
        s2 += __shfl_xor(s2, d);
      }
      float m = s1 * (1.0f / 128.0f);
      float var = s2 * (1.0f / 128.0f) - m * m;
      mu[r] = m;
      rs[r] = rsqrtf(var + 1e-5f);
    }
    unsigned int* Hr2 = (unsigned int*)smem;   // [32][128] u32 = (h_odd<<16)|h_even
    #pragma unroll
    for (int ot = 0; ot < 8; ++ot) {
      const int o = ot * 16 + l15;
      const float ga = lng[o], be = lnb[o];
      #pragma unroll
      for (int rp = 0; rp < 2; ++rp) {
        float v0 = yac[ot][rp * 2];
        float h0 = (v0 - mu[rp * 2]) * rs[rp * 2] * ga + be;
        h0 = h0 / (1.0f + expf(-h0));
        float v1 = yac[ot][rp * 2 + 1];
        float h1 = (v1 - mu[rp * 2 + 1]) * rs[rp * 2 + 1] * ga + be;
        h1 = h1 / (1.0f + expf(-h1));
        const int t2r = w * 8 + g * 2 + rp;
        Hr2[hr_idx(t2r, o)] = ((unsigned int)f2bf(h1) << 16) | (unsigned int)f2bf(h0);
      }
    }
  }
  __syncthreads();

  // ---- out GEMM: M=32 (t2) x N=128 (o), K=256 (c2); wave w owns o in [32w,32w+32) ----
  {
    unsigned int* Hr2 = (unsigned int*)smem;
    f32x4 oac[2][2] = {};
    #pragma unroll
    for (int kt = 0; kt < 8; ++kt) {
      const int k2 = kt * 32 + g * 8;
      bf16x8 af2[2];
      #pragma unroll
      for (int mt = 0; mt < 2; ++mt) {
        union { bf16x8 v; u32x4 u; } Aa;
        Aa.u = *(const u32x4*)&Hr2[hr_idx(mt * 16 + l15, kt * 16 + g * 4)];
        af2[mt] = Aa.v;
      }
      #pragma unroll
      for (int nt = 0; nt < 2; ++nt) {
        const int o = w * 32 + nt * 16 + l15;
        bf16x8 bfr = *(const bf16x8*)&Wb[o * NS + k2];
        #pragma unroll
        for (int mt = 0; mt < 2; ++mt)
          oac[mt][nt] = __builtin_amdgcn_mfma_f32_16x16x32_bf16(af2[mt], bfr, oac[mt][nt], 0, 0, 0);
      }
    }
    float* Ot = (float*)(smem + 16384);   // [128][stride 37] f32
    #pragma unroll
    for (int mt = 0; mt < 2; ++mt) {
      #pragma unroll
      for (int nt = 0; nt < 2; ++nt) {
        const int o = w * 32 + nt * 16 + l15;
        #pragma unroll
        for (int r = 0; r < 4; ++r)
          Ot[o * 37 + mt * 16 + g * 4 + r] = oac[mt][nt][r];
      }
    }
  }
  __syncthreads();

  // ---- epilogue: bias + coalesced float4 stores ----
  {
    const float* Ot = (const float*)(smem + 16384);
    const int o = tid >> 1;
    const int hf = tid & 1;
    const float bia = bias[o];
    float* gp = out + ((size_t)(b * OCH + o)) * THALF + kc * (CHUNK / 2) + hf * 16;
    #pragma unroll
    for (int i4 = 0; i4 < 4; ++i4) {
      float4 q;
      q.x = Ot[o * 37 + hf * 16 + i4 * 4 + 0] + bia;
      q.y = Ot[o * 37 + hf * 16 + i4 * 4 + 1] + bia;
      q.z = Ot[o * 37 + hf * 16 + i4 * 4 + 2] + bia;
      q.w = Ot[o * 37 + hf * 16 + i4 * 4 + 3] + bia;
      *(float4*)(gp + i4 * 4) = q;
    }
  }
}

// ---------------- launch ----------------
extern "C" void kernel_launch(void* const* d_in, const int* in_sizes, int n_in,
                              void* d_out, int out_size, void* d_ws, size_t ws_size,
                              hipStream_t stream) {
  const float* x    = (const float*)d_in[0];
  const float* rl   = (const float*)d_in[1];
  const float* Bc   = (const float*)d_in[2];
  const float* Cm   = (const float*)d_in[3];
  const float* lng  = (const float*)d_in[4];
  const float* lnb  = (const float*)d_in[5];
  const float* W    = (const float*)d_in[6];
  const float* bias = (const float*)d_in[7];
  float* out = (float*)d_out;

  char* ws = (char*)d_ws;
  unsigned short* BdT = (unsigned short*)(ws);            // 64 KB
  unsigned short* CT  = (unsigned short*)(ws + 65536);    // 64 KB
  unsigned short* Wb  = (unsigned short*)(ws + 131072);   // 64 KB
  float* Ad    = (float*)(ws + 196608);                   // 1 KB
  float* rL    = (float*)(ws + 197632);                   // 1 KB
  float* carry = (float*)(ws + 198656);                   // 2 MB

  k_prep<<<385, 256, 0, stream>>>(rl, Bc, Cm, W, BdT, CT, Wb, Ad, rL);
  k_pass<0><<<BATCH * NCHUNK, 256, 49152, stream>>>(x, BdT, CT, Wb, Ad, carry,
                                                    lng, lnb, bias, out);
  k_combine<<<64, 256, 0, stream>>>(carry, rL);
  k_pass<1><<<BATCH * NCHUNK, 256, 49152, stream>>>(x, BdT, CT, Wb, Ad, carry,
                                                    lng, lnb, bias, out);
}

// Round 2
// 152.482 us; speedup vs baseline: 1.0511x; 1.0511x over previous
//
#include <hip/hip_runtime.h>

#define BATCH 8
#define CIN 128
#define OCH 128
#define T_LEN 16384
#define NS 256
#define CHUNK 64
#define NCHUNK (T_LEN / CHUNK)   // 256
#define THALF (T_LEN / 2)        // 8192

typedef __attribute__((ext_vector_type(8))) short bf16x8;
typedef __attribute__((ext_vector_type(4))) float f32x4;
typedef __attribute__((ext_vector_type(4))) unsigned int u32x4;

__device__ __forceinline__ unsigned short f2bf(float f) {
  unsigned int u = __float_as_uint(f);
  u += 0x7fffu + ((u >> 16) & 1u);           // RNE
  return (unsigned short)(u >> 16);
}
__device__ __forceinline__ float bf2f(unsigned int h) {
  return __uint_as_float(h << 16);
}
__device__ __forceinline__ float softplusf_(float v) {
  return (v > 20.0f) ? v : log1pf(expf(v));
}
// XOR swizzles (16B-chunk granularity), bijective per row
__device__ __forceinline__ int xt_idx(int t, int c)  { return t * 128 + (c ^ ((t  & 7) << 3)); } // bf16 elems
__device__ __forceinline__ int v2_idx(int tp, int n) { return tp * 256 + (n ^ ((tp & 7) << 2)); } // u32 elems
__device__ __forceinline__ int hr_idx(int t2, int o) { return t2 * 128 + (o ^ ((t2 & 7) << 2)); } // u32 elems

// ---------------- prep: weights -> bf16, A_d, A_d^L ----------------
__global__ __launch_bounds__(256) void k_prep(
    const float* __restrict__ rl, const float* __restrict__ Bc,
    const float* __restrict__ Cm, const float* __restrict__ W,
    unsigned short* __restrict__ BdT, unsigned short* __restrict__ CT,
    unsigned short* __restrict__ Wb, float* __restrict__ Ad, float* __restrict__ rL)
{
  const int tid = blockIdx.x * 256 + threadIdx.x;
  if (tid < NS * CIN) {                       // BdT[n][c] = B_c[c][n] * (A_d-1)/lam
    const int n = tid >> 7, c = tid & 127;
    float lam = -softplusf_(rl[n]);
    float ad = expf(lam);
    float sc = (ad - 1.0f) / lam;
    BdT[tid] = f2bf(Bc[c * NS + n] * sc);
  } else if (tid < 2 * NS * CIN) {            // CT[o][n] = C[n][o]
    const int i = tid - NS * CIN;
    const int o = i >> 8, n = i & 255;
    CT[i] = f2bf(Cm[n * OCH + o]);
  } else if (tid < 3 * NS * CIN) {            // Wb[o][c2] = W[o][c2]
    const int i = tid - 2 * NS * CIN;
    Wb[i] = f2bf(W[i]);
  } else if (tid < 3 * NS * CIN + NS) {
    const int n = tid - 3 * NS * CIN;
    float lam = -softplusf_(rl[n]);
    Ad[n] = expf(lam);
    rL[n] = expf(lam * (float)CHUNK);
  }
}

// ---------------- chunk-carry combine: Hillis-Steele with multiplier A^L ----------------
__global__ __launch_bounds__(256) void k_combine(float* __restrict__ carry,
                                                 const float* __restrict__ rL)
{
  const int b = blockIdx.x >> 3;
  const int ng = blockIdx.x & 7;      // n-group of 32
  const int t = threadIdx.x;          // chunk index
  __shared__ float Y[32][NCHUNK];
  float* base = carry + ((size_t)b * NCHUNK + t) * NS + ng * 32;
  #pragma unroll
  for (int i4 = 0; i4 < 8; ++i4) {
    float4 q = *(const float4*)(base + i4 * 4);
    Y[i4 * 4 + 0][t] = q.x; Y[i4 * 4 + 1][t] = q.y;
    Y[i4 * 4 + 2][t] = q.z; Y[i4 * 4 + 3][t] = q.w;
  }
  float rp[32];
  #pragma unroll
  for (int i = 0; i < 32; ++i) rp[i] = rL[ng * 32 + i];
  __syncthreads();
  for (int d = 1; d < NCHUNK; d <<= 1) {
    float tmp[32];
    #pragma unroll
    for (int i = 0; i < 32; ++i) tmp[i] = (t >= d) ? Y[i][t - d] : 0.0f;
    __syncthreads();
    #pragma unroll
    for (int i = 0; i < 32; ++i) { Y[i][t] += rp[i] * tmp[i]; rp[i] *= rp[i]; }
    __syncthreads();
  }
  const int tm = (t == 0) ? 0 : (t - 1);
  #pragma unroll
  for (int i4 = 0; i4 < 8; ++i4) {
    float a = Y[i4 * 4 + 0][tm], bb = Y[i4 * 4 + 1][tm];
    float c = Y[i4 * 4 + 2][tm], dd = Y[i4 * 4 + 3][tm];
    float4 q;
    q.x = (t == 0) ? 0.0f : a;  q.y = (t == 0) ? 0.0f : bb;
    q.z = (t == 0) ? 0.0f : c;  q.w = (t == 0) ? 0.0f : dd;
    *(float4*)(base + i4 * 4) = q;
  }
}

// ---------------- main pass ----------------
// FULL=0: x -> v-GEMM -> in-register scan (seed 0) -> chunk carry.
// FULL=1: same, seeded from carry, then V2 pack -> y-GEMM -> LN+SiLU -> out-GEMM -> store.
template <int FULL>
__global__ __launch_bounds__(256, 4) void k_pass(
    const float* __restrict__ x,
    const unsigned short* __restrict__ BdT,
    const unsigned short* __restrict__ CT,
    const unsigned short* __restrict__ Wb,
    const float* __restrict__ Ad,
    float* __restrict__ carry,
    const float* __restrict__ lng, const float* __restrict__ lnb,
    const float* __restrict__ bias,
    float* __restrict__ out)
{
  const int bid = blockIdx.x;
  const int b = bid >> 8;               // batch
  const int kc = bid & (NCHUNK - 1);    // chunk
  const int t0 = kc * CHUNK;
  const int tid = threadIdx.x;
  const int w = tid >> 6;               // wave 0..3
  const int l = tid & 63;
  const int l15 = l & 15;
  const int g = l >> 4;

  extern __shared__ char smem[];
  unsigned short* Xt = (unsigned short*)smem;   // [64][128] bf16 swizzled (16 KB)
  unsigned int* V2 = (unsigned int*)smem;       // [32][256] u32, ALIASES Xt (32 KB, FULL only)

  // ---- stage x chunk transposed: Xt[t][c] = bf16(x[b][c][t0+t]) ----
  for (int i = tid; i < CHUNK * CIN; i += 256) {
    const int t = i & (CHUNK - 1);
    const int c = i >> 6;
    float v = x[((size_t)(b * CIN + c)) * T_LEN + (t0 + t)];
    Xt[xt_idx(t, c)] = f2bf(v);
  }
  __syncthreads();

  // ---- v GEMM: V[t][n] = Xt(64x128) . BdT^T ; wave w owns n in [64w, 64w+64) ----
  f32x4 acc[4][4] = {};
  #pragma unroll
  for (int kt = 0; kt < 4; ++kt) {
    const int kk = kt * 32 + g * 8;
    bf16x8 afr[4];
    #pragma unroll
    for (int mt = 0; mt < 4; ++mt)
      afr[mt] = *(const bf16x8*)&Xt[xt_idx(mt * 16 + l15, kk)];
    #pragma unroll
    for (int nt = 0; nt < 4; ++nt) {
      const int n = w * 64 + nt * 16 + l15;
      bf16x8 bfr = *(const bf16x8*)&BdT[n * CIN + kk];
      #pragma unroll
      for (int mt = 0; mt < 4; ++mt)
        acc[mt][nt] = __builtin_amdgcn_mfma_f32_16x16x32_bf16(afr[mt], bfr, acc[mt][nt], 0, 0, 0);
    }
  }

  // ---- in-register wave-local scan over t (acc element r <-> t = mt*16+g*4+r) ----
  // Per 4-lane column (same n, g=0..3): 3 serial FMAs local, Hillis-Steele over g
  // with ratio A^4, carry broadcast across mt blocks. No LDS, no barriers.
  #pragma unroll
  for (int nt = 0; nt < 4; ++nt) {
    const int n = w * 64 + nt * 16 + l15;
    const float a1 = Ad[n];
    const float a2 = a1 * a1, a3 = a2 * a1, a4 = a2 * a2;
    const float a8 = a4 * a4, a16 = a8 * a8;
    float a4g = 1.0f;
    if (g & 1) a4g *= a4;
    if (g & 2) a4g *= a8;
    const float m1 = (g >= 1) ? a4 : 0.0f;
    const float m2 = (g >= 2) ? a8 : 0.0f;
    float cr = 0.0f;
    if (FULL) cr = carry[((size_t)b * NCHUNK + kc) * NS + n];
    #pragma unroll
    for (int mt = 0; mt < 4; ++mt) {
      const float v0 = acc[mt][nt][0], v1 = acc[mt][nt][1];
      const float v2 = acc[mt][nt][2], v3 = acc[mt][nt][3];
      const float p0 = v0;
      const float p1 = fmaf(a1, p0, v1);
      const float p2 = fmaf(a1, p1, v2);
      const float p3 = fmaf(a1, p2, v3);
      float c0 = p3;
      float u = __shfl_up(c0, 16);
      c0 = fmaf(m1, u, c0);
      u = __shfl_up(c0, 32);
      c0 = fmaf(m2, u, c0);
      float e = __shfl_up(c0, 16);
      e = (g == 0) ? 0.0f : e;
      const float seed = fmaf(a4g, cr, e);
      acc[mt][nt][0] = fmaf(a1, seed, p0);
      acc[mt][nt][1] = fmaf(a2, seed, p1);
      acc[mt][nt][2] = fmaf(a3, seed, p2);
      acc[mt][nt][3] = fmaf(a4, seed, p3);
      const float ctop = __shfl(c0, 48 + l15);   // g=3 column total
      cr = fmaf(a16, cr, ctop);
    }
    if (!FULL) {
      if (g == 0) carry[((size_t)b * NCHUNK + kc) * NS + n] = cr;
    }
  }
  if (!FULL) return;

  // ---- pack states to V2 (bf16 pairs, swizzled) for the transpose ----
  __syncthreads();   // Xt dead; V2 aliases it
  #pragma unroll
  for (int mt = 0; mt < 4; ++mt) {
    #pragma unroll
    for (int nt = 0; nt < 4; ++nt) {
      const int n = w * 64 + nt * 16 + l15;
      #pragma unroll
      for (int rp = 0; rp < 2; ++rp) {
        const int tp = mt * 8 + g * 2 + rp;
        unsigned int pk = ((unsigned int)f2bf(acc[mt][nt][rp * 2 + 1]) << 16)
                        |  (unsigned int)f2bf(acc[mt][nt][rp * 2]);
        V2[v2_idx(tp, n)] = pk;
      }
    }
  }
  __syncthreads();

  // ---- y GEMM: wave w owns rows t in [16w, 16w+16), all 128 o ----
  f32x4 yac[8] = {};
  {
    const int trow = w * 16 + l15;
    const int tp = trow >> 1;
    const unsigned int sel = (trow & 1) ? 0x07060302u : 0x05040100u;
    #pragma unroll
    for (int kt = 0; kt < 8; ++kt) {
      const int n0 = kt * 32 + g * 8;
      u32x4 q0 = *(const u32x4*)&V2[v2_idx(tp, n0)];
      u32x4 q1 = *(const u32x4*)&V2[v2_idx(tp, n0 + 4)];
      union { bf16x8 v; unsigned int u[4]; } Af;
      Af.u[0] = __builtin_amdgcn_perm(q0[1], q0[0], sel);
      Af.u[1] = __builtin_amdgcn_perm(q0[3], q0[2], sel);
      Af.u[2] = __builtin_amdgcn_perm(q1[1], q1[0], sel);
      Af.u[3] = __builtin_amdgcn_perm(q1[3], q1[2], sel);
      #pragma unroll
      for (int ot = 0; ot < 8; ++ot) {
        const int o = ot * 16 + l15;
        bf16x8 bfr = *(const bf16x8*)&CT[o * NS + n0];
        yac[ot] = __builtin_amdgcn_mfma_f32_16x16x32_bf16(Af.v, bfr, yac[ot], 0, 0, 0);
      }
    }
  }

  // ---- LayerNorm (in-register 16-lane reduce) + SiLU, pack into Hr2 ----
  unsigned int hpk[8][2];
  {
    float mu[4], rs[4];
    #pragma unroll
    for (int r = 0; r < 4; ++r) {
      float s1 = 0.0f, s2 = 0.0f;
      #pragma unroll
      for (int ot = 0; ot < 8; ++ot) { float v = yac[ot][r]; s1 += v; s2 += v * v; }
      #pragma unroll
      for (int d = 1; d < 16; d <<= 1) {
        s1 += __shfl_xor(s1, d);
        s2 += __shfl_xor(s2, d);
      }
      float m = s1 * (1.0f / 128.0f);
      float var = s2 * (1.0f / 128.0f) - m * m;
      mu[r] = m;
      rs[r] = rsqrtf(var + 1e-5f);
    }
    #pragma unroll
    for (int ot = 0; ot < 8; ++ot) {
      const int o = ot * 16 + l15;
      const float ga = lng[o], be = lnb[o];
      #pragma unroll
      for (int rp = 0; rp < 2; ++rp) {
        float h0 = (yac[ot][rp * 2] - mu[rp * 2]) * rs[rp * 2] * ga + be;
        h0 = h0 * __builtin_amdgcn_rcpf(1.0f + __expf(-h0));
        float h1 = (yac[ot][rp * 2 + 1] - mu[rp * 2 + 1]) * rs[rp * 2 + 1] * ga + be;
        h1 = h1 * __builtin_amdgcn_rcpf(1.0f + __expf(-h1));
        hpk[ot][rp] = ((unsigned int)f2bf(h1) << 16) | (unsigned int)f2bf(h0);
      }
    }
  }
  __syncthreads();   // V2 dead; Hr2 aliases it
  {
    unsigned int* Hr2 = (unsigned int*)smem;   // [32][128] u32 (16 KB)
    #pragma unroll
    for (int ot = 0; ot < 8; ++ot) {
      const int o = ot * 16 + l15;
      #pragma unroll
      for (int rp = 0; rp < 2; ++rp) {
        const int t2r = w * 8 + g * 2 + rp;
        Hr2[hr_idx(t2r, o)] = hpk[ot][rp];
      }
    }
  }
  __syncthreads();

  // ---- out GEMM: M=32 (t2) x N=128 (o), K=256 (c2); direct global stores ----
  {
    const unsigned int* Hr2 = (const unsigned int*)smem;
    f32x4 oac[2][2] = {};
    #pragma unroll
    for (int kt = 0; kt < 8; ++kt) {
      const int k2 = kt * 32 + g * 8;
      bf16x8 af2[2];
      #pragma unroll
      for (int mt = 0; mt < 2; ++mt) {
        union { bf16x8 v; u32x4 u; } Aa;
        Aa.u = *(const u32x4*)&Hr2[hr_idx(mt * 16 + l15, kt * 16 + g * 4)];
        af2[mt] = Aa.v;
      }
      #pragma unroll
      for (int nt = 0; nt < 2; ++nt) {
        const int o = w * 32 + nt * 16 + l15;
        bf16x8 bfr = *(const bf16x8*)&Wb[o * NS + k2];
        #pragma unroll
        for (int mt = 0; mt < 2; ++mt)
          oac[mt][nt] = __builtin_amdgcn_mfma_f32_16x16x32_bf16(af2[mt], bfr, oac[mt][nt], 0, 0, 0);
      }
    }
    #pragma unroll
    for (int nt = 0; nt < 2; ++nt) {
      const int o = w * 32 + nt * 16 + l15;
      const float bia = bias[o];
      #pragma unroll
      for (int mt = 0; mt < 2; ++mt) {
        float4 q;
        q.x = oac[mt][nt][0] + bia;
        q.y = oac[mt][nt][1] + bia;
        q.z = oac[mt][nt][2] + bia;
        q.w = oac[mt][nt][3] + bia;
        float* gp = out + ((size_t)(b * OCH + o)) * THALF + kc * (CHUNK / 2) + mt * 16 + g * 4;
        *(float4*)gp = q;
      }
    }
  }
}

// ---------------- launch ----------------
extern "C" void kernel_launch(void* const* d_in, const int* in_sizes, int n_in,
                              void* d_out, int out_size, void* d_ws, size_t ws_size,
                              hipStream_t stream) {
  const float* x    = (const float*)d_in[0];
  const float* rl   = (const float*)d_in[1];
  const float* Bc   = (const float*)d_in[2];
  const float* Cm   = (const float*)d_in[3];
  const float* lng  = (const float*)d_in[4];
  const float* lnb  = (const float*)d_in[5];
  const float* W    = (const float*)d_in[6];
  const float* bias = (const float*)d_in[7];
  float* out = (float*)d_out;

  char* ws = (char*)d_ws;
  unsigned short* BdT = (unsigned short*)(ws);            // 64 KB
  unsigned short* CT  = (unsigned short*)(ws + 65536);    // 64 KB
  unsigned short* Wb  = (unsigned short*)(ws + 131072);   // 64 KB
  float* Ad    = (float*)(ws + 196608);                   // 1 KB
  float* rL    = (float*)(ws + 197632);                   // 1 KB
  float* carry = (float*)(ws + 198656);                   // 2 MB

  k_prep<<<385, 256, 0, stream>>>(rl, Bc, Cm, W, BdT, CT, Wb, Ad, rL);
  k_pass<0><<<BATCH * NCHUNK, 256, 16384, stream>>>(x, BdT, CT, Wb, Ad, carry,
                                                    lng, lnb, bias, out);
  k_combine<<<64, 256, 0, stream>>>(carry, rL);
  k_pass<1><<<BATCH * NCHUNK, 256, 32768, stream>>>(x, BdT, CT, Wb, Ad, carry,
                                                    lng, lnb, bias, out);
}

// Round 3
// 142.688 us; speedup vs baseline: 1.1232x; 1.0686x over previous
//
#include <hip/hip_runtime.h>

#define BATCH 8
#define CIN 128
#define OCH 128
#define T_LEN 16384
#define NS 256
#define CHUNK 64
#define NCHUNK (T_LEN / CHUNK)   // 256
#define THALF (T_LEN / 2)        // 8192

typedef __attribute__((ext_vector_type(8))) short bf16x8;
typedef __attribute__((ext_vector_type(4))) float f32x4;
typedef __attribute__((ext_vector_type(4))) unsigned int u32x4;

__device__ __forceinline__ unsigned short f2bf(float f) {
  unsigned int u = __float_as_uint(f);
  u += 0x7fffu + ((u >> 16) & 1u);           // RNE
  return (unsigned short)(u >> 16);
}
__device__ __forceinline__ float softplusf_(float v) {
  return (v > 20.0f) ? v : log1pf(expf(v));
}

// ---------------- prep: weights -> bf16, A_d, A_d^L ----------------
__global__ __launch_bounds__(256) void k_prep(
    const float* __restrict__ rl, const float* __restrict__ Bc,
    const float* __restrict__ Cm, const float* __restrict__ W,
    unsigned short* __restrict__ BdT, unsigned short* __restrict__ CT,
    unsigned short* __restrict__ Wb, float* __restrict__ Ad, float* __restrict__ rL)
{
  const int tid = blockIdx.x * 256 + threadIdx.x;
  if (tid < NS * CIN) {                       // BdT[n][c] = B_c[c][n] * (A_d-1)/lam
    const int n = tid >> 7, c = tid & 127;
    float lam = -softplusf_(rl[n]);
    float ad = expf(lam);
    float sc = (ad - 1.0f) / lam;
    BdT[tid] = f2bf(Bc[c * NS + n] * sc);
  } else if (tid < 2 * NS * CIN) {            // CT[o][n] = C[n][o]
    const int i = tid - NS * CIN;
    const int o = i >> 8, n = i & 255;
    CT[i] = f2bf(Cm[n * OCH + o]);
  } else if (tid < 3 * NS * CIN) {            // Wb[o][c2] = W[o][c2]
    const int i = tid - 2 * NS * CIN;
    Wb[i] = f2bf(W[i]);
  } else if (tid < 3 * NS * CIN + NS) {
    const int n = tid - 3 * NS * CIN;
    float lam = -softplusf_(rl[n]);
    Ad[n] = expf(lam);
    rL[n] = expf(lam * (float)CHUNK);
  }
}

// ---------------- chunk-carry combine: Hillis-Steele with multiplier A^L ----------------
__global__ __launch_bounds__(256) void k_combine(float* __restrict__ carry,
                                                 const float* __restrict__ rL)
{
  const int b = blockIdx.x >> 3;
  const int ng = blockIdx.x & 7;      // n-group of 32
  const int t = threadIdx.x;          // chunk index
  __shared__ float Y[32][NCHUNK];
  float* base = carry + ((size_t)b * NCHUNK + t) * NS + ng * 32;
  #pragma unroll
  for (int i4 = 0; i4 < 8; ++i4) {
    float4 q = *(const float4*)(base + i4 * 4);
    Y[i4 * 4 + 0][t] = q.x; Y[i4 * 4 + 1][t] = q.y;
    Y[i4 * 4 + 2][t] = q.z; Y[i4 * 4 + 3][t] = q.w;
  }
  float rp[32];
  #pragma unroll
  for (int i = 0; i < 32; ++i) rp[i] = rL[ng * 32 + i];
  __syncthreads();
  for (int d = 1; d < NCHUNK; d <<= 1) {
    float tmp[32];
    #pragma unroll
    for (int i = 0; i < 32; ++i) tmp[i] = (t >= d) ? Y[i][t - d] : 0.0f;
    __syncthreads();
    #pragma unroll
    for (int i = 0; i < 32; ++i) { Y[i][t] += rp[i] * tmp[i]; rp[i] *= rp[i]; }
    __syncthreads();
  }
  const int tm = (t == 0) ? 0 : (t - 1);
  #pragma unroll
  for (int i4 = 0; i4 < 8; ++i4) {
    float a = Y[i4 * 4 + 0][tm], bb = Y[i4 * 4 + 1][tm];
    float c = Y[i4 * 4 + 2][tm], dd = Y[i4 * 4 + 3][tm];
    float4 q;
    q.x = (t == 0) ? 0.0f : a;  q.y = (t == 0) ? 0.0f : bb;
    q.z = (t == 0) ? 0.0f : c;  q.w = (t == 0) ? 0.0f : dd;
    *(float4*)(base + i4 * 4) = q;
  }
}

// ---------------- main pass: persistent 8-wave blocks, NCHK chunks each ----------------
// FULL=0: x -> v-GEMM -> chunk totals (carry).  FULL=1: seeded scan -> y -> LN/SiLU -> out.
// Weights: BdT + Wb in registers (per-wave slices), CT in LDS (swizzled), loaded ONCE.
template <int FULL, int NCHK>
__global__ __launch_bounds__(512, FULL ? 2 : 4) void k_pass(
    const float* __restrict__ x,
    const unsigned short* __restrict__ BdT,
    const unsigned short* __restrict__ CT,
    const unsigned short* __restrict__ Wb,
    const float* __restrict__ Ad,
    float* __restrict__ carry,
    const float* __restrict__ lng, const float* __restrict__ lnb,
    const float* __restrict__ bias,
    float* __restrict__ out)
{
  constexpr int BPB = NCHUNK / NCHK;
  const int b   = blockIdx.x / BPB;
  const int seg = blockIdx.x % BPB;
  const int kc0 = seg * NCHK;

  const int tid = threadIdx.x;
  const int w = tid >> 6;               // wave 0..7
  const int l = tid & 63;
  const int l15 = l & 15;
  const int g = l >> 4;

  constexpr int SMEM_SZ = FULL ? (65536 + 2 * 16384 + 32768 + 2048) : (2 * 16384);
  __shared__ __align__(16) char smem[SMEM_SZ];
  unsigned short* CTl = (unsigned short*)smem;                    // 64 KB (FULL)
  char* XtBase = smem + (FULL ? 65536 : 0);                       // 2 x 16 KB
  unsigned int* V2l = (unsigned int*)(smem + (FULL ? 98304 : 0)); // 32 KB (FULL)
  float* Lex = (float*)(smem + (FULL ? 131072 : 0));              // 1 KB  (FULL)

  // ---- per-wave weight fragments in registers ----
  bf16x8 Bf[2][4];   // BdT slice: n in [32w, 32w+32)
  #pragma unroll
  for (int nt = 0; nt < 2; ++nt)
    #pragma unroll
    for (int kt = 0; kt < 4; ++kt)
      Bf[nt][kt] = *(const bf16x8*)&BdT[(w * 32 + nt * 16 + l15) * CIN + kt * 32 + g * 8];

  // scan constants (hoisted)
  float A1[2], A2[2], A3[2], A4[2], A8[2], A16[2], A4G[2], M1[2], M2[2];
  #pragma unroll
  for (int nt = 0; nt < 2; ++nt) {
    const float a1 = Ad[w * 32 + nt * 16 + l15];
    A1[nt] = a1; A2[nt] = a1 * a1; A3[nt] = A2[nt] * a1; A4[nt] = A2[nt] * A2[nt];
    A8[nt] = A4[nt] * A4[nt]; A16[nt] = A8[nt] * A8[nt];
    float a4g = 1.0f;
    if (g & 1) a4g *= A4[nt];
    if (g & 2) a4g *= A8[nt];
    A4G[nt] = a4g;
    M1[nt] = (g >= 1) ? A4[nt] : 0.0f;
    M2[nt] = (g >= 2) ? A8[nt] : 0.0f;
  }

  const int oh  = w >> 2;        // o-half for y-GEMM
  const int ow  = (w >> 1) * 32; // o-slice for out-GEMM
  const int mt2 = w & 1;         // t2-tile for out-GEMM
  bf16x8 Wf[2][8];
  float ga[4], be[4], bi[2];
  if constexpr (FULL) {
    #pragma unroll
    for (int nt = 0; nt < 2; ++nt) {
      #pragma unroll
      for (int kt = 0; kt < 8; ++kt)
        Wf[nt][kt] = *(const bf16x8*)&Wb[(ow + nt * 16 + l15) * NS + kt * 32 + g * 8];
      bi[nt] = bias[ow + nt * 16 + l15];
    }
    #pragma unroll
    for (int ot = 0; ot < 4; ++ot) {
      ga[ot] = lng[oh * 64 + ot * 16 + l15];
      be[ot] = lnb[oh * 64 + ot * 16 + l15];
    }
    // stage CT -> LDS once, swizzled: CTl[o][n ^ ((o&7)<<3)]
    #pragma unroll
    for (int j = 0; j < 8; ++j) {
      const int idx16 = j * 512 + tid;          // 4096 16B-chunks
      const int o = idx16 >> 5;
      const int n0 = (idx16 & 31) * 8;
      u32x4 q = *(const u32x4*)&CT[o * NS + n0];
      *(u32x4*)&CTl[o * NS + (n0 ^ ((o & 7) << 3))] = q;
    }
  }

  // ---- prefetch x for first chunk (lane = t, wave+j = c-pair: coalesced) ----
  float xa[8], xb[8];
  {
    const float* xp = x + (size_t)(b * CIN) * T_LEN + kc0 * CHUNK + l;
    #pragma unroll
    for (int j = 0; j < 8; ++j) {
      const int c2 = j * 8 + w;
      xa[j] = xp[(size_t)(2 * c2) * T_LEN];
      xb[j] = xp[(size_t)(2 * c2 + 1) * T_LEN];
    }
  }

  float crv[2] = {0.0f, 0.0f};
  if constexpr (FULL) {
    #pragma unroll
    for (int nt = 0; nt < 2; ++nt)
      crv[nt] = carry[((size_t)b * NCHUNK + kc0) * NS + (w * 32 + nt * 16 + l15)];
  }
  __syncthreads();   // CT staged

  int cur = 0;
  #pragma unroll 1
  for (int i = 0; i < NCHK; ++i) {
    const int kc = kc0 + i;

    // ---- convert prefetched x into Xt[cur] (swizzled bf16 pairs) ----
    {
      unsigned int* Xtu = (unsigned int*)(XtBase + cur * 16384);
      #pragma unroll
      for (int j = 0; j < 8; ++j) {
        const int c2 = j * 8 + w;
        unsigned int pk = ((unsigned int)f2bf(xb[j]) << 16) | (unsigned int)f2bf(xa[j]);
        Xtu[l * 64 + (c2 ^ ((l & 7) << 2))] = pk;
      }
    }
    __syncthreads();

    // ---- prefetch next chunk (hidden under compute) ----
    if (i + 1 < NCHK) {
      const float* xp = x + (size_t)(b * CIN) * T_LEN + (kc + 1) * CHUNK + l;
      #pragma unroll
      for (int j = 0; j < 8; ++j) {
        const int c2 = j * 8 + w;
        xa[j] = xp[(size_t)(2 * c2) * T_LEN];
        xb[j] = xp[(size_t)(2 * c2 + 1) * T_LEN];
      }
    }

    // ---- v-GEMM: V[64t][32n per wave], A from LDS, B from regs ----
    const unsigned short* Xts = (const unsigned short*)(XtBase + cur * 16384);
    f32x4 vac[4][2] = {};
    #pragma unroll
    for (int kt = 0; kt < 4; ++kt) {
      bf16x8 afr[4];
      #pragma unroll
      for (int mt = 0; mt < 4; ++mt)
        afr[mt] = *(const bf16x8*)&Xts[(mt * 16 + l15) * 128 + ((kt * 32 + g * 8) ^ ((l15 & 7) << 3))];
      #pragma unroll
      for (int nt = 0; nt < 2; ++nt)
        #pragma unroll
        for (int mt = 0; mt < 4; ++mt)
          vac[mt][nt] = __builtin_amdgcn_mfma_f32_16x16x32_bf16(afr[mt], Bf[nt][kt], vac[mt][nt], 0, 0, 0);
    }

    // ---- in-register scan over t (carry chained across chunks for FULL) ----
    if constexpr (!FULL) { crv[0] = 0.0f; crv[1] = 0.0f; }
    #pragma unroll
    for (int nt = 0; nt < 2; ++nt) {
      float cr = crv[nt];
      #pragma unroll
      for (int mt = 0; mt < 4; ++mt) {
        const float p0 = vac[mt][nt][0];
        const float p1 = fmaf(A1[nt], p0, vac[mt][nt][1]);
        const float p2 = fmaf(A1[nt], p1, vac[mt][nt][2]);
        const float p3 = fmaf(A1[nt], p2, vac[mt][nt][3]);
        float c0 = p3;
        float u = __shfl_up(c0, 16);
        c0 = fmaf(M1[nt], u, c0);
        u = __shfl_up(c0, 32);
        c0 = fmaf(M2[nt], u, c0);
        if constexpr (FULL) {
          float e = __shfl_up(c0, 16);
          e = (g == 0) ? 0.0f : e;
          const float seed = fmaf(A4G[nt], cr, e);
          vac[mt][nt][0] = fmaf(A1[nt], seed, p0);
          vac[mt][nt][1] = fmaf(A2[nt], seed, p1);
          vac[mt][nt][2] = fmaf(A3[nt], seed, p2);
          vac[mt][nt][3] = fmaf(A4[nt], seed, p3);
        }
        const float ctop = __shfl(c0, 48 + l15);
        cr = fmaf(A16[nt], cr, ctop);
      }
      crv[nt] = cr;
    }
    if constexpr (!FULL) {
      if (g == 0) {
        #pragma unroll
        for (int nt = 0; nt < 2; ++nt)
          carry[((size_t)b * NCHUNK + kc) * NS + (w * 32 + nt * 16 + l15)] = crv[nt];
      }
      cur ^= 1;
      continue;
    }

    // ---- pack states to V2 (bf16 t-pairs, swizzled) ----
    #pragma unroll
    for (int mt = 0; mt < 4; ++mt)
      #pragma unroll
      for (int nt = 0; nt < 2; ++nt) {
        const int n = w * 32 + nt * 16 + l15;
        #pragma unroll
        for (int rp = 0; rp < 2; ++rp) {
          const int tp = mt * 8 + g * 2 + rp;
          unsigned int pk = ((unsigned int)f2bf(vac[mt][nt][rp * 2 + 1]) << 16)
                          |  (unsigned int)f2bf(vac[mt][nt][rp * 2]);
          V2l[tp * 256 + (n ^ ((tp & 7) << 2))] = pk;
        }
      }
    __syncthreads();

    // ---- y-GEMM: wave = (t-tile w&3, o-half oh); CT from LDS ----
    f32x4 yac[4] = {};
    {
      const int trow = (w & 3) * 16 + l15;
      const int tp = trow >> 1;
      const unsigned int sel = (trow & 1) ? 0x07060302u : 0x05040100u;
      const int ssw = (tp & 7) << 2;
      const int csw = (l15 & 7) << 3;
      #pragma unroll
      for (int kt = 0; kt < 8; ++kt) {
        const int n0 = kt * 32 + g * 8;
        u32x4 q0 = *(const u32x4*)&V2l[tp * 256 + (n0 ^ ssw)];
        u32x4 q1 = *(const u32x4*)&V2l[tp * 256 + ((n0 + 4) ^ ssw)];
        union { bf16x8 v; unsigned int u[4]; } Af;
        Af.u[0] = __builtin_amdgcn_perm(q0[1], q0[0], sel);
        Af.u[1] = __builtin_amdgcn_perm(q0[3], q0[2], sel);
        Af.u[2] = __builtin_amdgcn_perm(q1[1], q1[0], sel);
        Af.u[3] = __builtin_amdgcn_perm(q1[3], q1[2], sel);
        #pragma unroll
        for (int ot = 0; ot < 4; ++ot) {
          bf16x8 bfr = *(const bf16x8*)&CTl[(oh * 64 + ot * 16 + l15) * NS + (n0 ^ csw)];
          yac[ot] = __builtin_amdgcn_mfma_f32_16x16x32_bf16(Af.v, bfr, yac[ot], 0, 0, 0);
        }
      }
    }

    // ---- LN partials (64 o per wave) + cross-wave exchange ----
    float s1v[4], s2v[4];
    #pragma unroll
    for (int r = 0; r < 4; ++r) {
      float s1 = 0.0f, s2 = 0.0f;
      #pragma unroll
      for (int ot = 0; ot < 4; ++ot) { const float v = yac[ot][r]; s1 += v; s2 = fmaf(v, v, s2); }
      #pragma unroll
      for (int d = 1; d < 16; d <<= 1) { s1 += __shfl_xor(s1, d); s2 += __shfl_xor(s2, d); }
      s1v[r] = s1; s2v[r] = s2;
    }
    if (l15 == 0) {
      #pragma unroll
      for (int r = 0; r < 4; ++r) {
        const int t = (w & 3) * 16 + g * 4 + r;
        *(float2*)&Lex[(t * 2 + oh) * 2] = make_float2(s1v[r], s2v[r]);
      }
    }
    __syncthreads();

    // ---- finish LN + SiLU, pack interleaved pairs into Hr2 (aliases V2) ----
    unsigned int* Hr2 = V2l;
    {
      float mu[4], rs[4];
      #pragma unroll
      for (int r = 0; r < 4; ++r) {
        const int t = (w & 3) * 16 + g * 4 + r;
        const float2 e0 = *(const float2*)&Lex[(t * 2 + 0) * 2];
        const float2 e1 = *(const float2*)&Lex[(t * 2 + 1) * 2];
        const float m = (e0.x + e1.x) * (1.0f / 128.0f);
        const float va = (e0.y + e1.y) * (1.0f / 128.0f) - m * m;
        mu[r] = m; rs[r] = rsqrtf(va + 1e-5f);
      }
      #pragma unroll
      for (int ot = 0; ot < 4; ++ot) {
        const int o = oh * 64 + ot * 16 + l15;
        #pragma unroll
        for (int rp = 0; rp < 2; ++rp) {
          float h0 = (yac[ot][rp * 2]     - mu[rp * 2])     * rs[rp * 2]     * ga[ot] + be[ot];
          h0 = h0 * __builtin_amdgcn_rcpf(1.0f + __expf(-h0));
          float h1 = (yac[ot][rp * 2 + 1] - mu[rp * 2 + 1]) * rs[rp * 2 + 1] * ga[ot] + be[ot];
          h1 = h1 * __builtin_amdgcn_rcpf(1.0f + __expf(-h1));
          const int t2 = (w & 3) * 8 + g * 2 + rp;
          Hr2[t2 * 128 + (o ^ ((t2 & 7) << 2))] =
              ((unsigned int)f2bf(h1) << 16) | (unsigned int)f2bf(h0);
        }
      }
    }
    __syncthreads();

    // ---- out-GEMM: wave = (t2-tile mt2, o-slice ow); Wb from regs; direct stores ----
    {
      const int t2row = mt2 * 16 + l15;
      const int hsw = (t2row & 7) << 2;
      f32x4 oac[2] = {};
      #pragma unroll
      for (int kt = 0; kt < 8; ++kt) {
        union { bf16x8 v; u32x4 u; } Aa;
        Aa.u = *(const u32x4*)&Hr2[t2row * 128 + ((kt * 16 + g * 4) ^ hsw)];
        #pragma unroll
        for (int nt = 0; nt < 2; ++nt)
          oac[nt] = __builtin_amdgcn_mfma_f32_16x16x32_bf16(Aa.v, Wf[nt][kt], oac[nt], 0, 0, 0);
      }
      #pragma unroll
      for (int nt = 0; nt < 2; ++nt) {
        const int o = ow + nt * 16 + l15;
        float4 q;
        q.x = oac[nt][0] + bi[nt];
        q.y = oac[nt][1] + bi[nt];
        q.z = oac[nt][2] + bi[nt];
        q.w = oac[nt][3] + bi[nt];
        *(float4*)(out + ((size_t)(b * OCH + o)) * THALF + kc * 32 + mt2 * 16 + g * 4) = q;
      }
    }
    cur ^= 1;
  }
}

// ---------------- launch ----------------
extern "C" void kernel_launch(void* const* d_in, const int* in_sizes, int n_in,
                              void* d_out, int out_size, void* d_ws, size_t ws_size,
                              hipStream_t stream) {
  const float* x    = (const float*)d_in[0];
  const float* rl   = (const float*)d_in[1];
  const float* Bc   = (const float*)d_in[2];
  const float* Cm   = (const float*)d_in[3];
  const float* lng  = (const float*)d_in[4];
  const float* lnb  = (const float*)d_in[5];
  const float* W    = (const float*)d_in[6];
  const float* bias = (const float*)d_in[7];
  float* out = (float*)d_out;

  char* ws = (char*)d_ws;
  unsigned short* BdT = (unsigned short*)(ws);            // 64 KB
  unsigned short* CT  = (unsigned short*)(ws + 65536);    // 64 KB
  unsigned short* Wb  = (unsigned short*)(ws + 131072);   // 64 KB
  float* Ad    = (float*)(ws + 196608);                   // 1 KB
  float* rL    = (float*)(ws + 197632);                   // 1 KB
  float* carry = (float*)(ws + 198656);                   // 2 MB

  k_prep<<<385, 256, 0, stream>>>(rl, Bc, Cm, W, BdT, CT, Wb, Ad, rL);
  k_pass<0, 2><<<BATCH * (NCHUNK / 2), 512, 0, stream>>>(x, BdT, CT, Wb, Ad, carry,
                                                         lng, lnb, bias, out);
  k_combine<<<64, 256, 0, stream>>>(carry, rL);
  k_pass<1, 8><<<BATCH * (NCHUNK / 8), 512, 0, stream>>>(x, BdT, CT, Wb, Ad, carry,
                                                         lng, lnb, bias, out);
}

// Round 4
// 121.697 us; speedup vs baseline: 1.3169x; 1.1725x over previous
//
#include <hip/hip_runtime.h>

#define BATCH 8
#define CIN 128
#define OCH 128
#define T_LEN 16384
#define NS 256
#define CHUNK 64
#define NCHUNK (T_LEN / CHUNK)   // 256
#define THALF (T_LEN / 2)        // 8192

#define SROW 260                 // scratch / V2 row stride (u32): 16B-aligned, bank-spreading
#define SCHUNK (32 * SROW)       // 8320 u32 per chunk image
#define HROW 132                 // Hr2 row stride (u32)

typedef __attribute__((ext_vector_type(8))) short bf16x8;
typedef __attribute__((ext_vector_type(4))) float f32x4;
typedef __attribute__((ext_vector_type(4))) unsigned int u32x4;
typedef __attribute__((ext_vector_type(2))) unsigned int u32x2;

__device__ __forceinline__ unsigned short f2bf(float f) {
  unsigned int u = __float_as_uint(f);
  u += 0x7fffu + ((u >> 16) & 1u);           // RNE
  return (unsigned short)(u >> 16);
}
__device__ __forceinline__ float bf2f(unsigned int h) {
  return __uint_as_float(h << 16);
}
__device__ __forceinline__ unsigned int pk2(float lo, float hi) {
  return ((unsigned int)f2bf(hi) << 16) | (unsigned int)f2bf(lo);
}
__device__ __forceinline__ float softplusf_(float v) {
  return (v > 20.0f) ? v : log1pf(expf(v));
}
// raw barrier: orders LDS ops without draining vmcnt (keeps global prefetch in flight)
__device__ __forceinline__ void rawbar() {
  __builtin_amdgcn_sched_barrier(0);
  asm volatile("s_waitcnt lgkmcnt(0)" ::: "memory");
  __builtin_amdgcn_sched_barrier(0);
  __builtin_amdgcn_s_barrier();
  __builtin_amdgcn_sched_barrier(0);
}

// ---------------- prep: weights -> bf16, A_d, A_d^L ----------------
__global__ __launch_bounds__(256) void k_prep(
    const float* __restrict__ rl, const float* __restrict__ Bc,
    const float* __restrict__ Cm, const float* __restrict__ W,
    unsigned short* __restrict__ BdT, unsigned short* __restrict__ CT,
    unsigned short* __restrict__ Wb, float* __restrict__ Ad, float* __restrict__ rL)
{
  const int tid = blockIdx.x * 256 + threadIdx.x;
  if (tid < NS * CIN) {                       // BdT[n][c] = B_c[c][n] * (A_d-1)/lam
    const int n = tid >> 7, c = tid & 127;
    float lam = -softplusf_(rl[n]);
    float ad = expf(lam);
    float sc = (ad - 1.0f) / lam;
    BdT[tid] = f2bf(Bc[c * NS + n] * sc);
  } else if (tid < 2 * NS * CIN) {            // CT[o][n] = C[n][o]
    const int i = tid - NS * CIN;
    const int o = i >> 8, n = i & 255;
    CT[i] = f2bf(Cm[n * OCH + o]);
  } else if (tid < 3 * NS * CIN) {            // Wb[o][c2] = W[o][c2]
    const int i = tid - 2 * NS * CIN;
    Wb[i] = f2bf(W[i]);
  } else if (tid < 3 * NS * CIN + NS) {
    const int n = tid - 3 * NS * CIN;
    float lam = -softplusf_(rl[n]);
    Ad[n] = expf(lam);
    rL[n] = expf(lam * (float)CHUNK);
  }
}

// ---------------- chunk-carry combine: Hillis-Steele with multiplier A^L ----------------
__global__ __launch_bounds__(256) void k_combine(float* __restrict__ carry,
                                                 const float* __restrict__ rL)
{
  const int b = blockIdx.x >> 3;
  const int ng = blockIdx.x & 7;      // n-group of 32
  const int t = threadIdx.x;          // chunk index
  __shared__ float Y[32][NCHUNK];
  float* base = carry + ((size_t)b * NCHUNK + t) * NS + ng * 32;
  #pragma unroll
  for (int i4 = 0; i4 < 8; ++i4) {
    float4 q = *(const float4*)(base + i4 * 4);
    Y[i4 * 4 + 0][t] = q.x; Y[i4 * 4 + 1][t] = q.y;
    Y[i4 * 4 + 2][t] = q.z; Y[i4 * 4 + 3][t] = q.w;
  }
  float rp[32];
  #pragma unroll
  for (int i = 0; i < 32; ++i) rp[i] = rL[ng * 32 + i];
  __syncthreads();
  for (int d = 1; d < NCHUNK; d <<= 1) {
    float tmp[32];
    #pragma unroll
    for (int i = 0; i < 32; ++i) tmp[i] = (t >= d) ? Y[i][t - d] : 0.0f;
    __syncthreads();
    #pragma unroll
    for (int i = 0; i < 32; ++i) { Y[i][t] += rp[i] * tmp[i]; rp[i] *= rp[i]; }
    __syncthreads();
  }
  const int tm = (t == 0) ? 0 : (t - 1);
  #pragma unroll
  for (int i4 = 0; i4 < 8; ++i4) {
    float a = Y[i4 * 4 + 0][tm], bb = Y[i4 * 4 + 1][tm];
    float c = Y[i4 * 4 + 2][tm], dd = Y[i4 * 4 + 3][tm];
    float4 q;
    q.x = (t == 0) ? 0.0f : a;  q.y = (t == 0) ? 0.0f : bb;
    q.z = (t == 0) ? 0.0f : c;  q.w = (t == 0) ? 0.0f : dd;
    *(float4*)(base + i4 * 4) = q;
  }
}

// ---------------- k_scan: x -> v-GEMM -> scan(seed 0) -> s0 scratch + totals ----------------
__global__ __launch_bounds__(512, 4) void k_scan(
    const float* __restrict__ x,
    const unsigned short* __restrict__ BdT,
    const float* __restrict__ Ad,
    unsigned int* __restrict__ s0,
    float* __restrict__ carry)
{
  const int bid = blockIdx.x;
  const int b = bid >> 8;
  const int kc = bid & 255;
  const int tid = threadIdx.x;
  const int w = tid >> 6, l = tid & 63, l15 = l & 15, g = l >> 4;

  __shared__ __align__(16) unsigned int Xt[64 * 64];  // [t][c2 ^ ((t&7)<<2)] packed bf16 pairs

  // ---- stage x: thread -> (c2 = w*8 + (l&7), t = (l>>3) + 8k) : 2-way-conflict writes ----
  {
    const int c2 = w * 8 + (l & 7);
    const int tb = l >> 3;
    const float* r0 = x + ((size_t)(b * CIN + 2 * c2)) * T_LEN + kc * CHUNK + tb;
    float xa[8], xb[8];
    #pragma unroll
    for (int k = 0; k < 8; ++k) {
      xa[k] = r0[8 * k];
      xb[k] = r0[(size_t)T_LEN + 8 * k];
    }
    #pragma unroll
    for (int k = 0; k < 8; ++k) {
      const int t = tb + 8 * k;
      Xt[t * 64 + (c2 ^ ((t & 7) << 2))] = pk2(xa[k], xb[k]);
    }
  }

  // ---- per-wave B fragments (n in [32w, 32w+32)) + scan constants ----
  bf16x8 Bf[2][4];
  #pragma unroll
  for (int nt = 0; nt < 2; ++nt)
    #pragma unroll
    for (int kt = 0; kt < 4; ++kt)
      Bf[nt][kt] = *(const bf16x8*)&BdT[(w * 32 + nt * 16 + l15) * CIN + kt * 32 + g * 8];

  float A1[2], A2[2], A3[2], A4[2], A8[2], A16[2], A4G[2], M1[2], M2[2];
  #pragma unroll
  for (int nt = 0; nt < 2; ++nt) {
    const float a1 = Ad[w * 32 + nt * 16 + l15];
    A1[nt] = a1; A2[nt] = a1 * a1; A3[nt] = A2[nt] * a1; A4[nt] = A2[nt] * A2[nt];
    A8[nt] = A4[nt] * A4[nt]; A16[nt] = A8[nt] * A8[nt];
    float a4g = 1.0f;
    if (g & 1) a4g *= A4[nt];
    if (g & 2) a4g *= A8[nt];
    A4G[nt] = a4g;
    M1[nt] = (g >= 1) ? A4[nt] : 0.0f;
    M2[nt] = (g >= 2) ? A8[nt] : 0.0f;
  }
  __syncthreads();

  // ---- v-GEMM ----
  f32x4 vac[4][2] = {};
  #pragma unroll
  for (int kt = 0; kt < 4; ++kt) {
    bf16x8 afr[4];
    #pragma unroll
    for (int mt = 0; mt < 4; ++mt)
      afr[mt] = *(const bf16x8*)&Xt[(mt * 16 + l15) * 64 + ((kt * 16 + g * 4) ^ ((l15 & 7) << 2))];
    #pragma unroll
    for (int nt = 0; nt < 2; ++nt)
      #pragma unroll
      for (int mt = 0; mt < 4; ++mt)
        vac[mt][nt] = __builtin_amdgcn_mfma_f32_16x16x32_bf16(afr[mt], Bf[nt][kt], vac[mt][nt], 0, 0, 0);
  }

  // ---- in-register scan over t, seed 0; produce values + totals ----
  float crv[2] = {0.0f, 0.0f};
  #pragma unroll
  for (int nt = 0; nt < 2; ++nt) {
    float cr = 0.0f;
    #pragma unroll
    for (int mt = 0; mt < 4; ++mt) {
      const float p0 = vac[mt][nt][0];
      const float p1 = fmaf(A1[nt], p0, vac[mt][nt][1]);
      const float p2 = fmaf(A1[nt], p1, vac[mt][nt][2]);
      const float p3 = fmaf(A1[nt], p2, vac[mt][nt][3]);
      float c0 = p3;
      float u = __shfl_up(c0, 16);
      c0 = fmaf(M1[nt], u, c0);
      u = __shfl_up(c0, 32);
      c0 = fmaf(M2[nt], u, c0);
      float e = __shfl_up(c0, 16);
      e = (g == 0) ? 0.0f : e;
      const float seed = fmaf(A4G[nt], cr, e);
      vac[mt][nt][0] = fmaf(A1[nt], seed, p0);
      vac[mt][nt][1] = fmaf(A2[nt], seed, p1);
      vac[mt][nt][2] = fmaf(A3[nt], seed, p2);
      vac[mt][nt][3] = fmaf(A4[nt], seed, p3);
      const float ctop = __shfl(c0, 48 + l15);
      cr = fmaf(A16[nt], cr, ctop);
    }
    crv[nt] = cr;
  }

  // ---- store packed s0 + totals ----
  unsigned int* sc = s0 + (size_t)(b * NCHUNK + kc) * SCHUNK;
  #pragma unroll
  for (int mt = 0; mt < 4; ++mt)
    #pragma unroll
    for (int nt = 0; nt < 2; ++nt) {
      const int n = w * 32 + nt * 16 + l15;
      #pragma unroll
      for (int rp = 0; rp < 2; ++rp) {
        const int tp = mt * 8 + g * 2 + rp;
        sc[tp * SROW + n] = pk2(vac[mt][nt][rp * 2], vac[mt][nt][rp * 2 + 1]);
      }
    }
  if (g == 0) {
    #pragma unroll
    for (int nt = 0; nt < 2; ++nt)
      carry[((size_t)b * NCHUNK + kc) * NS + (w * 32 + nt * 16 + l15)] = crv[nt];
  }
}

// ---------------- k_apply: s0 + seed -> y -> LN/SiLU -> out ----------------
template <int NCHK>
__global__ __launch_bounds__(512, 4) void k_apply(
    const unsigned int* __restrict__ s0,
    const unsigned short* __restrict__ CT,
    const unsigned short* __restrict__ Wb,
    const float* __restrict__ Ad,
    const float* __restrict__ carry,
    const float* __restrict__ lng, const float* __restrict__ lnb,
    const float* __restrict__ bias,
    float* __restrict__ out)
{
  const int bid = blockIdx.x;
  const int b = bid / (NCHUNK / NCHK);
  const int kc0 = (bid % (NCHUNK / NCHK)) * NCHK;
  const int tid = threadIdx.x;
  const int w = tid >> 6, l = tid & 63, l15 = l & 15, g = l >> 4;

  __shared__ __align__(16) unsigned int V2[2][SCHUNK];  // 2 x 33280 B
  __shared__ __align__(16) float Lexf[64 * 8];          // [t][oq] (s1,s2)

  // correction mapping: thread -> (npair, tpg)
  const int npair = tid & 127, tpg = tid >> 7;
  const int nc0 = 2 * npair;
  const float cA0 = Ad[nc0], cA1 = Ad[nc0 + 1];
  const float cA0s = cA0 * cA0, cA1s = cA1 * cA1;
  float p0w = cA0, p1w = cA1;   // A^{16*tpg+1}
  {
    float a2 = cA0s, a4 = a2 * a2, a8 = a4 * a4, a16 = a8 * a8;
    float b2 = cA1s, b4 = b2 * b2, b8 = b4 * b4, b16 = b8 * b8;
    if (tpg & 1) { p0w *= a16; p1w *= b16; }
    if (tpg & 2) { p0w *= a16 * a16; p1w *= b16 * b16; }
  }

  // y mapping: wave = (tt = w>>2, oq = w&3); out mapping: o-eighth = w
  const int tt = w >> 2, oq = w & 3;
  float ga[2], be[2];
  #pragma unroll
  for (int ot = 0; ot < 2; ++ot) {
    ga[ot] = lng[oq * 32 + ot * 16 + l15];
    be[ot] = lnb[oq * 32 + ot * 16 + l15];
  }
  const float bia = bias[w * 16 + l15];
  const unsigned int sel = (l15 & 1) ? 0x07060302u : 0x05040100u;

  // prologue: stage chunk kc0 into V2[0]
  u32x4 st[4]; u32x4 stt = {};
  {
    const unsigned int* scb = s0 + (size_t)(b * NCHUNK + kc0) * SCHUNK;
    #pragma unroll
    for (int r = 0; r < 4; ++r) st[r] = *(const u32x4*)&scb[tid * 16 + r * 4];
    if (tid < 32) stt = *(const u32x4*)&scb[8192 + tid * 4];
    #pragma unroll
    for (int r = 0; r < 4; ++r) *(u32x4*)&V2[0][tid * 16 + r * 4] = st[r];
    if (tid < 32) *(u32x4*)&V2[0][8192 + tid * 4] = stt;
  }

  int cur = 0;
  #pragma unroll 1
  for (int i = 0; i < NCHK; ++i) {
    const int kc = kc0 + i;

    // issue next chunk's global loads (land during this iteration's compute)
    if (i + 1 < NCHK) {
      const unsigned int* scb = s0 + (size_t)(b * NCHUNK + kc + 1) * SCHUNK;
      #pragma unroll
      for (int r = 0; r < 4; ++r) st[r] = *(const u32x4*)&scb[tid * 16 + r * 4];
      if (tid < 32) stt = *(const u32x4*)&scb[8192 + tid * 4];
    }
    rawbar();   // V2[cur] staged & visible

    // ---- in-place seed correction: s = s0 + A^{t+1} * seed ----
    {
      const float* sd = carry + ((size_t)b * NCHUNK + kc) * NS;
      float e0 = sd[nc0] * p0w;
      float e1 = sd[nc0 + 1] * p1w;
      unsigned int* Vc = &V2[cur][(tpg * 8) * SROW + nc0];
      #pragma unroll
      for (int j = 0; j < 8; ++j) {
        u32x2 q = *(const u32x2*)&Vc[j * SROW];
        float v00 = bf2f(q[0] & 0xffffu) + e0;
        float v01 = bf2f(q[0] >> 16) + e0 * cA0;
        float v10 = bf2f(q[1] & 0xffffu) + e1;
        float v11 = bf2f(q[1] >> 16) + e1 * cA1;
        q[0] = pk2(v00, v01);
        q[1] = pk2(v10, v11);
        *(u32x2*)&Vc[j * SROW] = q;
        e0 *= cA0s;
        e1 *= cA1s;
      }
    }
    rawbar();

    // ---- y-GEMM: wave (tt, oq): 32 t x 32 o, K = 256 ----
    f32x4 yac[2][2] = {};
    #pragma unroll
    for (int kt = 0; kt < 8; ++kt) {
      const int n0 = kt * 32 + g * 8;
      bf16x8 Af[2];
      #pragma unroll
      for (int mt = 0; mt < 2; ++mt) {
        const int tp = (tt * 32 + mt * 16 + l15) >> 1;
        u32x4 q0 = *(const u32x4*)&V2[cur][tp * SROW + n0];
        u32x4 q1 = *(const u32x4*)&V2[cur][tp * SROW + n0 + 4];
        union { bf16x8 v; unsigned int u[4]; } Aa;
        Aa.u[0] = __builtin_amdgcn_perm(q0[1], q0[0], sel);
        Aa.u[1] = __builtin_amdgcn_perm(q0[3], q0[2], sel);
        Aa.u[2] = __builtin_amdgcn_perm(q1[1], q1[0], sel);
        Aa.u[3] = __builtin_amdgcn_perm(q1[3], q1[2], sel);
        Af[mt] = Aa.v;
      }
      #pragma unroll
      for (int ot = 0; ot < 2; ++ot) {
        bf16x8 bfr = *(const bf16x8*)&CT[(oq * 32 + ot * 16 + l15) * NS + n0];
        #pragma unroll
        for (int mt = 0; mt < 2; ++mt)
          yac[mt][ot] = __builtin_amdgcn_mfma_f32_16x16x32_bf16(Af[mt], bfr, yac[mt][ot], 0, 0, 0);
      }
    }

    // ---- LN partials -> Lex ----
    #pragma unroll
    for (int mt = 0; mt < 2; ++mt)
      #pragma unroll
      for (int r = 0; r < 4; ++r) {
        float s1 = yac[mt][0][r] + yac[mt][1][r];
        float s2 = yac[mt][0][r] * yac[mt][0][r] + yac[mt][1][r] * yac[mt][1][r];
        #pragma unroll
        for (int d = 1; d < 16; d <<= 1) { s1 += __shfl_xor(s1, d); s2 += __shfl_xor(s2, d); }
        if (l15 == 0) {
          const int t = tt * 32 + mt * 16 + g * 4 + r;
          *(float2*)&Lexf[t * 8 + oq * 2] = make_float2(s1, s2);
        }
      }
    rawbar();

    // ---- LN finish + SiLU -> Hr2 (aliases V2[cur]) ----
    unsigned int* Hr2 = &V2[cur][0];
    #pragma unroll
    for (int mt = 0; mt < 2; ++mt) {
      float mu[4], rs[4];
      #pragma unroll
      for (int r = 0; r < 4; ++r) {
        const int t = tt * 32 + mt * 16 + g * 4 + r;
        float4 f0 = *(const float4*)&Lexf[t * 8];
        float4 f1 = *(const float4*)&Lexf[t * 8 + 4];
        const float m = (f0.x + f0.z + f1.x + f1.z) * (1.0f / 128.0f);
        const float va = (f0.y + f0.w + f1.y + f1.w) * (1.0f / 128.0f) - m * m;
        mu[r] = m;
        rs[r] = rsqrtf(va + 1e-5f);
      }
      #pragma unroll
      for (int ot = 0; ot < 2; ++ot) {
        const int o = oq * 32 + ot * 16 + l15;
        #pragma unroll
        for (int rp = 0; rp < 2; ++rp) {
          float h0 = (yac[mt][ot][rp * 2] - mu[rp * 2]) * rs[rp * 2] * ga[ot] + be[ot];
          h0 = h0 * __builtin_amdgcn_rcpf(1.0f + __expf(-h0));
          float h1 = (yac[mt][ot][rp * 2 + 1] - mu[rp * 2 + 1]) * rs[rp * 2 + 1] * ga[ot] + be[ot];
          h1 = h1 * __builtin_amdgcn_rcpf(1.0f + __expf(-h1));
          const int t2 = tt * 16 + mt * 8 + g * 2 + rp;
          Hr2[t2 * HROW + o] = pk2(h0, h1);
        }
      }
    }
    rawbar();

    // ---- out-GEMM: wave w owns o in [16w, 16w+16), M = 32 t2, K = 256 ----
    {
      f32x4 oac[2] = {};
      #pragma unroll
      for (int kt = 0; kt < 8; ++kt) {
        bf16x8 Aa[2];
        #pragma unroll
        for (int mt = 0; mt < 2; ++mt) {
          union { bf16x8 v; u32x4 u; } Ax;
          Ax.u = *(const u32x4*)&Hr2[(mt * 16 + l15) * HROW + kt * 16 + g * 4];
          Aa[mt] = Ax.v;
        }
        bf16x8 bfr = *(const bf16x8*)&Wb[(w * 16 + l15) * NS + kt * 32 + g * 8];
        #pragma unroll
        for (int mt = 0; mt < 2; ++mt)
          oac[mt] = __builtin_amdgcn_mfma_f32_16x16x32_bf16(Aa[mt], bfr, oac[mt], 0, 0, 0);
      }
      const int o = w * 16 + l15;
      #pragma unroll
      for (int mt = 0; mt < 2; ++mt) {
        float4 q;
        q.x = oac[mt][0] + bia;
        q.y = oac[mt][1] + bia;
        q.z = oac[mt][2] + bia;
        q.w = oac[mt][3] + bia;
        *(float4*)(out + ((size_t)(b * OCH + o)) * THALF + kc * 32 + mt * 16 + g * 4) = q;
      }
    }

    // ---- write staged next chunk into the other buffer ----
    if (i + 1 < NCHK) {
      #pragma unroll
      for (int r = 0; r < 4; ++r) *(u32x4*)&V2[cur ^ 1][tid * 16 + r * 4] = st[r];
      if (tid < 32) *(u32x4*)&V2[cur ^ 1][8192 + tid * 4] = stt;
    }
    cur ^= 1;
  }
}

// ---------------- R3 fallback (used if workspace too small for scratch) ----------------
__device__ __forceinline__ int xt_idx(int t, int c)  { return t * 128 + (c ^ ((t  & 7) << 3)); }
__device__ __forceinline__ int v2_idx(int tp, int n) { return tp * 256 + (n ^ ((tp & 7) << 2)); }
__device__ __forceinline__ int hr_idx(int t2, int o) { return t2 * 128 + (o ^ ((t2 & 7) << 2)); }

template <int FULL, int NCHK>
__global__ __launch_bounds__(512, FULL ? 2 : 4) void k_pass_fb(
    const float* __restrict__ x,
    const unsigned short* __restrict__ BdT,
    const unsigned short* __restrict__ CT,
    const unsigned short* __restrict__ Wb,
    const float* __restrict__ Ad,
    float* __restrict__ carry,
    const float* __restrict__ lng, const float* __restrict__ lnb,
    const float* __restrict__ bias,
    float* __restrict__ out)
{
  constexpr int BPB = NCHUNK / NCHK;
  const int b   = blockIdx.x / BPB;
  const int seg = blockIdx.x % BPB;
  const int kc0 = seg * NCHK;
  const int tid = threadIdx.x;
  const int w = tid >> 6, l = tid & 63, l15 = l & 15, g = l >> 4;

  constexpr int SMEM_SZ = FULL ? (65536 + 2 * 16384 + 32768 + 2048) : (2 * 16384);
  __shared__ __align__(16) char smem[SMEM_SZ];
  unsigned short* CTl = (unsigned short*)smem;
  char* XtBase = smem + (FULL ? 65536 : 0);
  unsigned int* V2l = (unsigned int*)(smem + (FULL ? 98304 : 0));
  float* Lex = (float*)(smem + (FULL ? 131072 : 0));

  bf16x8 Bf[2][4];
  #pragma unroll
  for (int nt = 0; nt < 2; ++nt)
    #pragma unroll
    for (int kt = 0; kt < 4; ++kt)
      Bf[nt][kt] = *(const bf16x8*)&BdT[(w * 32 + nt * 16 + l15) * CIN + kt * 32 + g * 8];

  float A1[2], A2[2], A3[2], A4[2], A8[2], A16[2], A4G[2], M1[2], M2[2];
  #pragma unroll
  for (int nt = 0; nt < 2; ++nt) {
    const float a1 = Ad[w * 32 + nt * 16 + l15];
    A1[nt] = a1; A2[nt] = a1 * a1; A3[nt] = A2[nt] * a1; A4[nt] = A2[nt] * A2[nt];
    A8[nt] = A4[nt] * A4[nt]; A16[nt] = A8[nt] * A8[nt];
    float a4g = 1.0f;
    if (g & 1) a4g *= A4[nt];
    if (g & 2) a4g *= A8[nt];
    A4G[nt] = a4g;
    M1[nt] = (g >= 1) ? A4[nt] : 0.0f;
    M2[nt] = (g >= 2) ? A8[nt] : 0.0f;
  }

  const int oh  = w >> 2;
  const int ow  = (w >> 1) * 32;
  const int mt2 = w & 1;
  bf16x8 Wf[2][8];
  float ga[4], be[4], bi[2];
  if constexpr (FULL) {
    #pragma unroll
    for (int nt = 0; nt < 2; ++nt) {
      #pragma unroll
      for (int kt = 0; kt < 8; ++kt)
        Wf[nt][kt] = *(const bf16x8*)&Wb[(ow + nt * 16 + l15) * NS + kt * 32 + g * 8];
      bi[nt] = bias[ow + nt * 16 + l15];
    }
    #pragma unroll
    for (int ot = 0; ot < 4; ++ot) {
      ga[ot] = lng[oh * 64 + ot * 16 + l15];
      be[ot] = lnb[oh * 64 + ot * 16 + l15];
    }
    #pragma unroll
    for (int j = 0; j < 8; ++j) {
      const int idx16 = j * 512 + tid;
      const int o = idx16 >> 5;
      const int n0 = (idx16 & 31) * 8;
      u32x4 q = *(const u32x4*)&CT[o * NS + n0];
      *(u32x4*)&CTl[o * NS + (n0 ^ ((o & 7) << 3))] = q;
    }
  }

  float xa[8], xb[8];
  {
    const float* xp = x + (size_t)(b * CIN) * T_LEN + kc0 * CHUNK + l;
    #pragma unroll
    for (int j = 0; j < 8; ++j) {
      const int c2 = j * 8 + w;
      xa[j] = xp[(size_t)(2 * c2) * T_LEN];
      xb[j] = xp[(size_t)(2 * c2 + 1) * T_LEN];
    }
  }

  float crv[2] = {0.0f, 0.0f};
  if constexpr (FULL) {
    #pragma unroll
    for (int nt = 0; nt < 2; ++nt)
      crv[nt] = carry[((size_t)b * NCHUNK + kc0) * NS + (w * 32 + nt * 16 + l15)];
  }
  __syncthreads();

  int cur = 0;
  #pragma unroll 1
  for (int i = 0; i < NCHK; ++i) {
    const int kc = kc0 + i;
    {
      unsigned int* Xtu = (unsigned int*)(XtBase + cur * 16384);
      #pragma unroll
      for (int j = 0; j < 8; ++j) {
        const int c2 = j * 8 + w;
        Xtu[l * 64 + (c2 ^ ((l & 7) << 2))] = pk2(xa[j], xb[j]);
      }
    }
    __syncthreads();
    if (i + 1 < NCHK) {
      const float* xp = x + (size_t)(b * CIN) * T_LEN + (kc + 1) * CHUNK + l;
      #pragma unroll
      for (int j = 0; j < 8; ++j) {
        const int c2 = j * 8 + w;
        xa[j] = xp[(size_t)(2 * c2) * T_LEN];
        xb[j] = xp[(size_t)(2 * c2 + 1) * T_LEN];
      }
    }
    const unsigned short* Xts = (const unsigned short*)(XtBase + cur * 16384);
    f32x4 vac[4][2] = {};
    #pragma unroll
    for (int kt = 0; kt < 4; ++kt) {
      bf16x8 afr[4];
      #pragma unroll
      for (int mt = 0; mt < 4; ++mt)
        afr[mt] = *(const bf16x8*)&Xts[(mt * 16 + l15) * 128 + ((kt * 32 + g * 8) ^ ((l15 & 7) << 3))];
      #pragma unroll
      for (int nt = 0; nt < 2; ++nt)
        #pragma unroll
        for (int mt = 0; mt < 4; ++mt)
          vac[mt][nt] = __builtin_amdgcn_mfma_f32_16x16x32_bf16(afr[mt], Bf[nt][kt], vac[mt][nt], 0, 0, 0);
    }
    if constexpr (!FULL) { crv[0] = 0.0f; crv[1] = 0.0f; }
    #pragma unroll
    for (int nt = 0; nt < 2; ++nt) {
      float cr = crv[nt];
      #pragma unroll
      for (int mt = 0; mt < 4; ++mt) {
        const float p0 = vac[mt][nt][0];
        const float p1 = fmaf(A1[nt], p0, vac[mt][nt][1]);
        const float p2 = fmaf(A1[nt], p1, vac[mt][nt][2]);
        const float p3 = fmaf(A1[nt], p2, vac[mt][nt][3]);
        float c0 = p3;
        float u = __shfl_up(c0, 16);
        c0 = fmaf(M1[nt], u, c0);
        u = __shfl_up(c0, 32);
        c0 = fmaf(M2[nt], u, c0);
        if constexpr (FULL) {
          float e = __shfl_up(c0, 16);
          e = (g == 0) ? 0.0f : e;
          const float seed = fmaf(A4G[nt], cr, e);
          vac[mt][nt][0] = fmaf(A1[nt], seed, p0);
          vac[mt][nt][1] = fmaf(A2[nt], seed, p1);
          vac[mt][nt][2] = fmaf(A3[nt], seed, p2);
          vac[mt][nt][3] = fmaf(A4[nt], seed, p3);
        }
        const float ctop = __shfl(c0, 48 + l15);
        cr = fmaf(A16[nt], cr, ctop);
      }
      crv[nt] = cr;
    }
    if constexpr (!FULL) {
      if (g == 0) {
        #pragma unroll
        for (int nt = 0; nt < 2; ++nt)
          carry[((size_t)b * NCHUNK + kc) * NS + (w * 32 + nt * 16 + l15)] = crv[nt];
      }
      cur ^= 1;
      continue;
    }
    #pragma unroll
    for (int mt = 0; mt < 4; ++mt)
      #pragma unroll
      for (int nt = 0; nt < 2; ++nt) {
        const int n = w * 32 + nt * 16 + l15;
        #pragma unroll
        for (int rp = 0; rp < 2; ++rp) {
          const int tp = mt * 8 + g * 2 + rp;
          V2l[v2_idx(tp, n)] = pk2(vac[mt][nt][rp * 2], vac[mt][nt][rp * 2 + 1]);
        }
      }
    __syncthreads();
    f32x4 yac[4] = {};
    {
      const int trow = (w & 3) * 16 + l15;
      const int tp = trow >> 1;
      const unsigned int sel = (trow & 1) ? 0x07060302u : 0x05040100u;
      const int ssw = (tp & 7) << 2;
      const int csw = (l15 & 7) << 3;
      #pragma unroll
      for (int kt = 0; kt < 8; ++kt) {
        const int n0 = kt * 32 + g * 8;
        u32x4 q0 = *(const u32x4*)&V2l[tp * 256 + (n0 ^ ssw)];
        u32x4 q1 = *(const u32x4*)&V2l[tp * 256 + ((n0 + 4) ^ ssw)];
        union { bf16x8 v; unsigned int u[4]; } Af;
        Af.u[0] = __builtin_amdgcn_perm(q0[1], q0[0], sel);
        Af.u[1] = __builtin_amdgcn_perm(q0[3], q0[2], sel);
        Af.u[2] = __builtin_amdgcn_perm(q1[1], q1[0], sel);
        Af.u[3] = __builtin_amdgcn_perm(q1[3], q1[2], sel);
        #pragma unroll
        for (int ot = 0; ot < 4; ++ot) {
          bf16x8 bfr = *(const bf16x8*)&CTl[(oh * 64 + ot * 16 + l15) * NS + (n0 ^ csw)];
          yac[ot] = __builtin_amdgcn_mfma_f32_16x16x32_bf16(Af.v, bfr, yac[ot], 0, 0, 0);
        }
      }
    }
    float s1v[4], s2v[4];
    #pragma unroll
    for (int r = 0; r < 4; ++r) {
      float s1 = 0.0f, s2 = 0.0f;
      #pragma unroll
      for (int ot = 0; ot < 4; ++ot) { const float v = yac[ot][r]; s1 += v; s2 = fmaf(v, v, s2); }
      #pragma unroll
      for (int d = 1; d < 16; d <<= 1) { s1 += __shfl_xor(s1, d); s2 += __shfl_xor(s2, d); }
      s1v[r] = s1; s2v[r] = s2;
    }
    if (l15 == 0) {
      #pragma unroll
      for (int r = 0; r < 4; ++r) {
        const int t = (w & 3) * 16 + g * 4 + r;
        *(float2*)&Lex[(t * 2 + oh) * 2] = make_float2(s1v[r], s2v[r]);
      }
    }
    __syncthreads();
    unsigned int* Hr2 = V2l;
    {
      float mu[4], rs[4];
      #pragma unroll
      for (int r = 0; r < 4; ++r) {
        const int t = (w & 3) * 16 + g * 4 + r;
        const float2 e0 = *(const float2*)&Lex[(t * 2 + 0) * 2];
        const float2 e1 = *(const float2*)&Lex[(t * 2 + 1) * 2];
        const float m = (e0.x + e1.x) * (1.0f / 128.0f);
        const float va = (e0.y + e1.y) * (1.0f / 128.0f) - m * m;
        mu[r] = m; rs[r] = rsqrtf(va + 1e-5f);
      }
      #pragma unroll
      for (int ot = 0; ot < 4; ++ot) {
        const int o = oh * 64 + ot * 16 + l15;
        #pragma unroll
        for (int rp = 0; rp < 2; ++rp) {
          float h0 = (yac[ot][rp * 2]     - mu[rp * 2])     * rs[rp * 2]     * ga[ot] + be[ot];
          h0 = h0 * __builtin_amdgcn_rcpf(1.0f + __expf(-h0));
          float h1 = (yac[ot][rp * 2 + 1] - mu[rp * 2 + 1]) * rs[rp * 2 + 1] * ga[ot] + be[ot];
          h1 = h1 * __builtin_amdgcn_rcpf(1.0f + __expf(-h1));
          const int t2 = (w & 3) * 8 + g * 2 + rp;
          Hr2[hr_idx(t2, o)] = pk2(h0, h1);
        }
      }
    }
    __syncthreads();
    {
      const int t2row = mt2 * 16 + l15;
      const int hsw = (t2row & 7) << 2;
      f32x4 oac[2] = {};
      #pragma unroll
      for (int kt = 0; kt < 8; ++kt) {
        union { bf16x8 v; u32x4 u; } Aa;
        Aa.u = *(const u32x4*)&Hr2[t2row * 128 + ((kt * 16 + g * 4) ^ hsw)];
        #pragma unroll
        for (int nt = 0; nt < 2; ++nt)
          oac[nt] = __builtin_amdgcn_mfma_f32_16x16x32_bf16(Aa.v, Wf[nt][kt], oac[nt], 0, 0, 0);
      }
      #pragma unroll
      for (int nt = 0; nt < 2; ++nt) {
        const int o = ow + nt * 16 + l15;
        float4 q;
        q.x = oac[nt][0] + bi[nt];
        q.y = oac[nt][1] + bi[nt];
        q.z = oac[nt][2] + bi[nt];
        q.w = oac[nt][3] + bi[nt];
        *(float4*)(out + ((size_t)(b * OCH + o)) * THALF + kc * 32 + mt2 * 16 + g * 4) = q;
      }
    }
    cur ^= 1;
  }
}

// ---------------- launch ----------------
extern "C" void kernel_launch(void* const* d_in, const int* in_sizes, int n_in,
                              void* d_out, int out_size, void* d_ws, size_t ws_size,
                              hipStream_t stream) {
  const float* x    = (const float*)d_in[0];
  const float* rl   = (const float*)d_in[1];
  const float* Bc   = (const float*)d_in[2];
  const float* Cm   = (const float*)d_in[3];
  const float* lng  = (const float*)d_in[4];
  const float* lnb  = (const float*)d_in[5];
  const float* W    = (const float*)d_in[6];
  const float* bias = (const float*)d_in[7];
  float* out = (float*)d_out;

  char* ws = (char*)d_ws;
  unsigned short* BdT = (unsigned short*)(ws);            // 64 KB
  unsigned short* CT  = (unsigned short*)(ws + 65536);    // 64 KB
  unsigned short* Wb  = (unsigned short*)(ws + 131072);   // 64 KB
  float* Ad    = (float*)(ws + 196608);                   // 1 KB
  float* rL    = (float*)(ws + 197632);                   // 1 KB
  float* carry = (float*)(ws + 198656);                   // 2 MB
  const size_t scr_off = 198656 + 2097152;
  unsigned int* s0 = (unsigned int*)(ws + scr_off);
  const size_t need = scr_off + (size_t)BATCH * NCHUNK * SCHUNK * 4;  // ~70.5 MB

  k_prep<<<385, 256, 0, stream>>>(rl, Bc, Cm, W, BdT, CT, Wb, Ad, rL);
  if (ws_size >= need) {
    k_scan<<<BATCH * NCHUNK, 512, 0, stream>>>(x, BdT, Ad, s0, carry);
    k_combine<<<64, 256, 0, stream>>>(carry, rL);
    k_apply<4><<<BATCH * (NCHUNK / 4), 512, 0, stream>>>(s0, CT, Wb, Ad, carry,
                                                         lng, lnb, bias, out);
  } else {
    k_pass_fb<0, 2><<<BATCH * (NCHUNK / 2), 512, 0, stream>>>(x, BdT, CT, Wb, Ad, carry,
                                                              lng, lnb, bias, out);
    k_combine<<<64, 256, 0, stream>>>(carry, rL);
    k_pass_fb<1, 8><<<BATCH * (NCHUNK / 8), 512, 0, stream>>>(x, BdT, CT, Wb, Ad, carry,
                                                              lng, lnb, bias, out);
  }
}